// Round 3
// baseline (406.390 us; speedup 1.0000x reference)
//
#include <hip/hip_runtime.h>

// Problem constants (from reference)
#define BB      4096
#define EE      128
#define MM      8
#define NSTEPS  3
#define HH      256
#define CC      16

#define TS      16                    // samples per tile (MFMA M-tile)
#define FB      1024                  // ushorts per weight frag-block (512 hi + 512 lo)

// frag-block ranges in wf:
//   W_in  : (m*8+nt)*4+kc            -> [0,256)
//   W_bias: 256 + (m*8+nt)*4+kc      -> [256,512)
//   W_f   : 512 + (m*8+nt)*8+kc      -> [512,1024)
//   W1    : 1024 + nt*4+kc (nt<16)   -> [1024,1088)
//   W2    : 1088 + kc      (kc<8)    -> [1088,1096)
#define NFRAGBLK 1096

#define NSEG    8                     // scatter segments per step (4096/512)
#define GRIDN   256                   // persistent stepper blocks (co-resident)
#define PREP_GRID (NFRAGBLK + NSTEPS*NSEG + 8)   // 1096 + 24 + 8 = 1128

typedef __attribute__((ext_vector_type(8))) short  bf16x8;
typedef __attribute__((ext_vector_type(4))) float  f32x4;

__device__ __forceinline__ unsigned short bf16_rn(float v) {
    unsigned u = __float_as_uint(v);
    return (unsigned short)((u + 0x7FFFu + ((u >> 16) & 1u)) >> 16);
}
__device__ __forceinline__ float bf16_f(unsigned short h) {
    return __uint_as_float(((unsigned)h) << 16);
}
__device__ __forceinline__ void split8(const float* v, bf16x8& hi, bf16x8& lo) {
    #pragma unroll
    for (int i = 0; i < 8; i++) {
        unsigned short h = bf16_rn(v[i]);
        hi[i] = (short)h;
        lo[i] = (short)bf16_rn(v[i] - bf16_f(h));
    }
}
__device__ __forceinline__ void split1(float v, unsigned short& h, unsigned short& l) {
    h = bf16_rn(v);
    l = bf16_rn(v - bf16_f(h));
}
#define MFMA(a,b,c) __builtin_amdgcn_mfma_f32_16x16x32_bf16((a),(b),(c),0,0,0)
__device__ __forceinline__ f32x4 mfma3(bf16x8 ah, bf16x8 al, bf16x8 bh, bf16x8 bl, f32x4 c) {
    c = MFMA(ah, bh, c);
    c = MFMA(ah, bl, c);
    c = MFMA(al, bh, c);
    return c;
}

// ---------------------------------------------------------------------------
// prep: weight convert | deterministic segmented scatter | flag zeroing.
// No atomics anywhere -> no memset node needed. Scatter segment = 512 samples
// of one step handled by one block; per-(t,m,seg) counts to wcnt, sample ids
// to perm[t][m][seg][0..511] in deterministic (seg, wave, lane) order.
// ---------------------------------------------------------------------------
__global__ __launch_bounds__(512) void prep_kernel(
    const int*   __restrict__ module_ids,
    const float* __restrict__ W_in, const float* __restrict__ W_bias,
    const float* __restrict__ W_f,  const float* __restrict__ W1,
    const float* __restrict__ W2,
    unsigned short* __restrict__ wf,
    int* __restrict__ wcnt, int* __restrict__ perm, int* __restrict__ fl)
{
    const int vb = blockIdx.x, tid = threadIdx.x;
    __shared__ int wc8[8][MM];

    if (vb < NFRAGBLK) {
        // ---- weight convert (B-fragment-linear, hi/lo split); 512 elems ----
        unsigned short* dhi = wf + (size_t)vb * FB;
        unsigned short* dlo = dhi + 512;
        const int el = tid;
        const int ln = el >> 3, j = el & 7;
        const int krel = ((ln >> 4) << 3) + j;    // 0..31
        const int nrel = ln & 15;
        float v;
        if (vb < 512) {
            const int bb = vb & 255;
            const int kc = bb & 3, nt = (bb >> 2) & 7, m = bb >> 5;
            const float* src = (vb < 256 ? W_in : W_bias) + (size_t)m * EE * EE;
            v = src[(size_t)(kc*32 + krel) * EE + nt*16 + nrel];
        } else if (vb < 1024) {
            const int bb = vb - 512;
            const int kc = bb & 7, nt = (bb >> 3) & 7, m = bb >> 6;
            v = W_f[(size_t)m * 2*EE*EE + (size_t)(kc*32 + krel) * EE + nt*16 + nrel];
        } else if (vb < 1088) {
            const int bb = vb - 1024;
            const int kc = bb & 3, nt = bb >> 2;
            v = W1[(size_t)(kc*32 + krel) * HH + nt*16 + nrel];
        } else {
            const int kc = vb - 1088;
            v = W2[(size_t)(kc*32 + krel) * CC + nrel];
        }
        split1(v, dhi[el], dlo[el]);
    } else if (vb < NFRAGBLK + NSTEPS*NSEG) {
        // ---- segmented scatter: block = (t, seg of 512 samples) ----
        const int u = vb - NFRAGBLK;              // 0..23
        const int t = u >> 3, seg = u & 7;
        const int lane = tid & 63, wave = tid >> 6;
        const int s = seg*512 + tid;
        const int m = module_ids[s*NSTEPS + t];
        unsigned long long mybal = 0ull, lanebal = 0ull;
        #pragma unroll
        for (int k = 0; k < MM; k++) {
            const unsigned long long bk = __ballot(m == k);
            if (m == k)    mybal   = bk;          // static index: cndmask
            if (lane == k) lanebal = bk;
        }
        if (lane < MM) wc8[wave][lane] = __popcll(lanebal);
        __syncthreads();
        int base = 0;
        #pragma unroll
        for (int w = 0; w < 8; w++) if (w < wave) base += wc8[w][m];
        const unsigned long long below = (1ull << lane) - 1ull;
        const int rank = __popcll(mybal & below);
        perm[(((t*MM + m)*NSEG) + seg)*512 + base + rank] = s;
        if (tid < MM) {
            int sum = 0;
            #pragma unroll
            for (int w = 0; w < 8; w++) sum += wc8[w][tid];
            wcnt[((t*MM + tid)*NSEG) + seg] = sum;
        }
    } else {
        // ---- zero per-sample step flags ----
        const int u = vb - NFRAGBLK - NSTEPS*NSEG;   // 0..7
        fl[u*512 + tid] = 0;
    }
}

// ---------------------------------------------------------------------------
// steps: persistent 256-block kernel running all 3 recurrent steps + head.
// Cross-step dependence handled by per-sample flags: each sample is written
// by exactly one tile per step and read by exactly one tile in the next, so
// producer (release-store fl[s]=t+1) -> consumer (poll + acquire) is the only
// cross-block edge. No grid barrier. All embedding rows gathered fp32
// directly (split-bf16 in-register, numerics identical to prestaging).
// ---------------------------------------------------------------------------
__global__ __launch_bounds__(512, 2) void steps_kernel(
    const int*   __restrict__ entity_ids,
    const float* __restrict__ embedding,
    const float* __restrict__ b_in, const float* __restrict__ b_bias,
    const float* __restrict__ b_f,
    const float* __restrict__ b1v, const float* __restrict__ b2,
    const unsigned short* __restrict__ wf,
    const int* __restrict__ wcnt, const int* __restrict__ perm,
    unsigned short* __restrict__ xsh, unsigned short* __restrict__ xsl,
    int* __restrict__ fl, float* __restrict__ out)
{
    const int bx = blockIdx.x, tid = threadIdx.x;
    const int lane = tid & 63, wave = tid >> 6;          // wave = n-tile (0..7)
    const int row16 = lane & 15, quad = lane >> 4;

    __shared__ __align__(16) unsigned short hfh[8][512]; // frag-linear A, hi
    __shared__ __align__(16) unsigned short hfl[8][512]; // lo
    __shared__ int   sids[TS];
    __shared__ float red[8][TS][CC];

    for (int t = 0; t < NSTEPS; t++) {
        // uniform bucket map for this step
        int tot[MM];
        #pragma unroll
        for (int k = 0; k < MM; k++) {
            int s = 0;
            #pragma unroll
            for (int j = 0; j < NSEG; j++) s += wcnt[(t*MM + k)*NSEG + j];
            tot[k] = s;
        }
        int NB = 0;
        #pragma unroll
        for (int k = 0; k < MM; k++) NB += (tot[k] + TS - 1) >> 4;

        for (int pass = 0; pass < 2; pass++) {
            const int vb = bx + pass*GRIDN;
            if (vb >= NB) break;                         // uniform per block

            int m = -1, pref = 0, cm = 0, acc = 0;
            #pragma unroll
            for (int k = 0; k < MM; k++) {
                const int nbk = (tot[k] + TS - 1) >> 4;
                if (m < 0 && vb < acc + nbk) { m = k; pref = acc; cm = tot[k]; }
                acc += nbk;
            }
            const int chunk = vb - pref;

            __syncthreads();   // LDS reuse guard across tiles
            if (tid < TS) {
                const int sl = chunk*TS + tid;
                int sv = -1;
                if (sl < cm) {
                    int j = 0, r = sl;
                    while (true) {
                        const int c = wcnt[(t*MM + m)*NSEG + j];
                        if (r < c) break;
                        r -= c; j++;
                    }
                    sv = perm[((t*MM + m)*NSEG + j)*512 + r];
                }
                sids[tid] = sv;
            }
            __syncthreads();

            const int sA  = sids[row16];
            const int sAc = sA < 0 ? 0 : sA;

            // operand fragments: x (xh/xl) and bias-embedding (eh/el)
            bf16x8 xh[4], xl[4], eh[4], el_[4];
            const int eidb = entity_ids[sAc*(NSTEPS+1) + t + 1];
            const float* srcb = embedding + (size_t)eidb*EE;

            if (t == 0) {
                const int eid0 = entity_ids[sAc*(NSTEPS+1)];
                const float* src0 = embedding + (size_t)eid0*EE;
                #pragma unroll
                for (int kc = 0; kc < 4; kc++) {
                    const int off = kc*32 + quad*8;
                    float vv[8], bb[8];
                    *(float4*)(vv)     = *(const float4*)(src0 + off);
                    *(float4*)(vv + 4) = *(const float4*)(src0 + off + 4);
                    *(float4*)(bb)     = *(const float4*)(srcb + off);
                    *(float4*)(bb + 4) = *(const float4*)(srcb + off + 4);
                    split8(vv, xh[kc], xl[kc]);
                    split8(bb, eh[kc], el_[kc]);
                }
            } else {
                // issue independent bias-row loads, then wait on producers
                float bb[4][8];
                #pragma unroll
                for (int kc = 0; kc < 4; kc++) {
                    const int off = kc*32 + quad*8;
                    *(float4*)(bb[kc])     = *(const float4*)(srcb + off);
                    *(float4*)(bb[kc] + 4) = *(const float4*)(srcb + off + 4);
                }
                if (tid < TS && sids[tid] >= 0) {
                    int* f = &fl[sids[tid]];
                    while (__hip_atomic_load(f, __ATOMIC_RELAXED, __HIP_MEMORY_SCOPE_AGENT) < t)
                        __builtin_amdgcn_s_sleep(2);
                    (void)__hip_atomic_load(f, __ATOMIC_ACQUIRE, __HIP_MEMORY_SCOPE_AGENT);
                }
                __syncthreads();

                const unsigned short* xhp = xsh + (size_t)sAc*EE;
                const unsigned short* xlp = xsl + (size_t)sAc*EE;
                #pragma unroll
                for (int kc = 0; kc < 4; kc++) {
                    const int off = kc*32 + quad*8;
                    xh[kc] = *(const bf16x8*)(xhp + off);
                    xl[kc] = *(const bf16x8*)(xlp + off);
                    split8(bb[kc], eh[kc], el_[kc]);
                }
            }

            // phase 1: h_in, h_bi for this wave's 16 output cols
            f32x4 aci = {0.f,0.f,0.f,0.f}, acb = {0.f,0.f,0.f,0.f};
            #pragma unroll
            for (int kc = 0; kc < 4; kc++) {
                const unsigned short* bI  = wf + (size_t)((m*8 + wave)*4 + kc)*FB;
                const unsigned short* bBp = wf + (size_t)(256 + (m*8 + wave)*4 + kc)*FB;
                const bf16x8 wih = *(const bf16x8*)(bI + lane*8);
                const bf16x8 wil = *(const bf16x8*)(bI + 512 + lane*8);
                const bf16x8 wbh = *(const bf16x8*)(bBp + lane*8);
                const bf16x8 wbl = *(const bf16x8*)(bBp + 512 + lane*8);
                aci = mfma3(xh[kc], xl[kc], wih, wil, aci);
                acb = mfma3(eh[kc], el_[kc], wbh, wbl, acb);
            }

            // epilogue 1: relu+bias, producer-side split, frag-linear LDS store
            {
                const int col = wave*16 + row16;
                const float bin = b_in [m*EE + col];
                const float bbi = b_bias[m*EE + col];
                #pragma unroll
                for (int r = 0; r < 4; r++) {
                    const int row = quad*4 + r;
                    {   // h_in -> k = col
                        const float v = fmaxf(aci[r] + bin, 0.f);
                        const int k = col, kc = k >> 5;
                        const int idx = (row + 16*((k >> 3) & 3))*8 + (k & 7);
                        split1(v, hfh[kc][idx], hfl[kc][idx]);
                    }
                    {   // h_bi -> k = 128 + col
                        const float v = fmaxf(acb[r] + bbi, 0.f);
                        const int k = EE + col, kc = k >> 5;
                        const int idx = (row + 16*((k >> 3) & 3))*8 + (k & 7);
                        split1(v, hfh[kc][idx], hfl[kc][idx]);
                    }
                }
            }
            __syncthreads();

            // phase 2: x_new = tanh(h W_f + b_f), K = 256
            f32x4 acf = {0.f,0.f,0.f,0.f};
            #pragma unroll
            for (int kc = 0; kc < 8; kc++) {
                const bf16x8 ah = *(const bf16x8*)(&hfh[kc][lane*8]);
                const bf16x8 al = *(const bf16x8*)(&hfl[kc][lane*8]);
                const unsigned short* bF = wf + (size_t)(512 + (m*8 + wave)*8 + kc)*FB;
                const bf16x8 wfh = *(const bf16x8*)(bF + lane*8);
                const bf16x8 wfl = *(const bf16x8*)(bF + 512 + lane*8);
                acf = mfma3(ah, al, wfh, wfl, acf);
            }

            const int col = wave*16 + row16;
            const float bfv = b_f[m*EE + col];
            float xv[4];
            #pragma unroll
            for (int r = 0; r < 4; r++) xv[r] = tanhf(acf[r] + bfv);

            if (t < NSTEPS-1) {
                // publish x_new: stores -> barrier (drains vmcnt) -> release flags
                #pragma unroll
                for (int r = 0; r < 4; r++) {
                    const int s = sids[quad*4 + r];
                    if (s >= 0) {
                        unsigned short h, l;
                        split1(xv[r], h, l);
                        xsh[(size_t)s*EE + col] = h;
                        xsl[(size_t)s*EE + col] = l;
                    }
                }
                __syncthreads();
                if (tid < TS && sids[tid] >= 0)
                    __hip_atomic_store(&fl[sids[tid]], t+1,
                                       __ATOMIC_RELEASE, __HIP_MEMORY_SCOPE_AGENT);
            } else {
                // ---- fused head: x stays on-chip ----
                __syncthreads();               // all waves done reading hf
                #pragma unroll
                for (int r = 0; r < 4; r++) {  // restage x split into hf kc 0..3
                    const int row = quad*4 + r;
                    const int k = col, kc = k >> 5;
                    const int idx = (row + 16*((k >> 3) & 3))*8 + (k & 7);
                    split1(xv[r], hfh[kc][idx], hfl[kc][idx]);
                }
                __syncthreads();

                // h = relu(x W1 + b1): 16 n-tiles, 2 per wave
                f32x4 a1[2] = {{0.f,0.f,0.f,0.f},{0.f,0.f,0.f,0.f}};
                #pragma unroll
                for (int i = 0; i < 2; i++) {
                    const int nt = wave + 8*i;
                    #pragma unroll
                    for (int kc = 0; kc < 4; kc++) {
                        const unsigned short* bW = wf + (size_t)(1024 + nt*4 + kc)*FB;
                        const bf16x8 wh = *(const bf16x8*)(bW + lane*8);
                        const bf16x8 wl = *(const bf16x8*)(bW + 512 + lane*8);
                        const bf16x8 ah = *(const bf16x8*)(&hfh[kc][lane*8]);
                        const bf16x8 al = *(const bf16x8*)(&hfl[kc][lane*8]);
                        a1[i] = mfma3(ah, al, wh, wl, a1[i]);
                    }
                }
                __syncthreads();               // done reading x before h overwrite
                #pragma unroll
                for (int i = 0; i < 2; i++) {
                    const int c2 = (wave + 8*i)*16 + row16;      // 0..255
                    const float b = b1v[c2];
                    #pragma unroll
                    for (int r = 0; r < 4; r++) {
                        const int row = quad*4 + r;
                        const float v = fmaxf(a1[i][r] + b, 0.f);
                        const int kc = c2 >> 5;
                        const int idx = (row + 16*((c2 >> 3) & 3))*8 + (c2 & 7);
                        split1(v, hfh[kc][idx], hfl[kc][idx]);
                    }
                }
                __syncthreads();

                // out = h W2 + b2: K-split, wave = kc
                f32x4 a2 = {0.f,0.f,0.f,0.f};
                {
                    const int kc = wave;
                    const bf16x8 ah = *(const bf16x8*)(&hfh[kc][lane*8]);
                    const bf16x8 al = *(const bf16x8*)(&hfl[kc][lane*8]);
                    const unsigned short* bW = wf + (size_t)(1088 + kc)*FB;
                    const bf16x8 wh = *(const bf16x8*)(bW + lane*8);
                    const bf16x8 wl = *(const bf16x8*)(bW + 512 + lane*8);
                    a2 = mfma3(ah, al, wh, wl, a2);
                }
                #pragma unroll
                for (int r = 0; r < 4; r++) red[wave][quad*4 + r][row16] = a2[r];
                __syncthreads();

                if (tid < TS*CC) {
                    const int sr = sids[tid >> 4];
                    if (sr >= 0) {
                        const int c = tid & 15;
                        float v = b2[c];
                        #pragma unroll
                        for (int w = 0; w < 8; w++) v += red[w][tid >> 4][c];
                        out[(size_t)sr*CC + c] = v;
                    }
                }
            }
        }
    }
}

// ---------------------------------------------------------------------------
extern "C" void kernel_launch(void* const* d_in, const int* in_sizes, int n_in,
                              void* d_out, int out_size, void* d_ws, size_t ws_size,
                              hipStream_t stream) {
    const int*   entity_ids = (const int*)  d_in[0];
    const int*   module_ids = (const int*)  d_in[1];
    const float* embedding  = (const float*)d_in[2];
    const float* W_in   = (const float*)d_in[3];
    const float* b_in   = (const float*)d_in[4];
    const float* W_bias = (const float*)d_in[5];
    const float* b_bias = (const float*)d_in[6];
    const float* W_f    = (const float*)d_in[7];
    const float* b_f    = (const float*)d_in[8];
    const float* W1     = (const float*)d_in[9];
    const float* b1     = (const float*)d_in[10];
    const float* W2     = (const float*)d_in[11];
    const float* b2     = (const float*)d_in[12];
    float* out = (float*)d_out;

    char* ws = (char*)d_ws;
    int* wcnt = (int*)(ws + 0);                           // 768 B
    int* perm = (int*)(ws + 4096);                        // 3*8*8*512*4 = 384 KB
    int* fl   = (int*)(ws + (512u<<10));                  // 16 KB
    unsigned short* wfb = (unsigned short*)(ws + (1u<<20));     // 2.25 MB
    unsigned short* xsh = (unsigned short*)(ws + (4u<<20));     // 1 MB each
    unsigned short* xsl = (unsigned short*)(ws + (5u<<20));

    prep_kernel<<<PREP_GRID, 512, 0, stream>>>(module_ids,
                                               W_in, W_bias, W_f, W1, W2,
                                               wfb, wcnt, perm, fl);

    void* sargs[] = { &entity_ids, &embedding, &b_in, &b_bias, &b_f,
                      &b1, &b2, &wfb, &wcnt, &perm, &xsh, &xsl, &fl, &out };
    hipError_t e = hipLaunchCooperativeKernel(
        reinterpret_cast<const void*>(steps_kernel),
        dim3(GRIDN), dim3(512), sargs, 0u, stream);
    if (e != hipSuccess) {
        (void)hipGetLastError();   // clear; plain launch (256 blocks co-reside)
        steps_kernel<<<GRIDN, 512, 0, stream>>>(entity_ids, embedding,
                                                b_in, b_bias, b_f, b1, b2,
                                                wfb, wcnt, perm, xsh, xsl, fl, out);
    }
}

// Round 4
// 365.653 us; speedup vs baseline: 1.1114x; 1.1114x over previous
//
#include <hip/hip_runtime.h>

// Problem constants (from reference)
#define BB      4096
#define EE      128
#define MM      8
#define NSTEPS  3
#define HH      256
#define CC      16

#define TS      16                    // samples per tile (MFMA M-tile)
#define FB      1024                  // ushorts per weight frag-block (512 hi + 512 lo)

// frag-block ranges in wf:
//   W_in  : (m*8+nt)*4+kc            -> [0,256)
//   W_bias: 256 + (m*8+nt)*4+kc      -> [256,512)
//   W_f   : 512 + (m*8+nt)*8+kc      -> [512,1024)
//   W1    : 1024 + nt*4+kc (nt<16)   -> [1024,1088)
//   W2    : 1088 + kc      (kc<8)    -> [1088,1096)
#define NFRAGBLK 1096

#define NSEG    8                     // scatter segments per step (4096/512)
#define NBMAX   (BB/TS + MM)          // 264 worst-case bucket tiles per step
#define PREP_GRID (NFRAGBLK + NSTEPS*NSEG)   // 1096 + 24 = 1120

typedef __attribute__((ext_vector_type(8))) short  bf16x8;
typedef __attribute__((ext_vector_type(4))) float  f32x4;

__device__ __forceinline__ unsigned short bf16_rn(float v) {
    unsigned u = __float_as_uint(v);
    return (unsigned short)((u + 0x7FFFu + ((u >> 16) & 1u)) >> 16);
}
__device__ __forceinline__ float bf16_f(unsigned short h) {
    return __uint_as_float(((unsigned)h) << 16);
}
__device__ __forceinline__ void split8(const float* v, bf16x8& hi, bf16x8& lo) {
    #pragma unroll
    for (int i = 0; i < 8; i++) {
        unsigned short h = bf16_rn(v[i]);
        hi[i] = (short)h;
        lo[i] = (short)bf16_rn(v[i] - bf16_f(h));
    }
}
__device__ __forceinline__ void split1(float v, unsigned short& h, unsigned short& l) {
    h = bf16_rn(v);
    l = bf16_rn(v - bf16_f(h));
}
#define MFMA(a,b,c) __builtin_amdgcn_mfma_f32_16x16x32_bf16((a),(b),(c),0,0,0)
__device__ __forceinline__ f32x4 mfma3(bf16x8 ah, bf16x8 al, bf16x8 bh, bf16x8 bl, f32x4 c) {
    c = MFMA(ah, bh, c);
    c = MFMA(ah, bl, c);
    c = MFMA(al, bh, c);
    return c;
}

// ---------------------------------------------------------------------------
// prep: weight convert | deterministic segmented scatter. No atomics, no
// memset dependency: every wcnt entry is written each run. Embedding is NOT
// prestaged — steps gather fp32 rows directly (traffic-neutral, verified R3).
// ---------------------------------------------------------------------------
__global__ __launch_bounds__(512) void prep_kernel(
    const int*   __restrict__ module_ids,
    const float* __restrict__ W_in, const float* __restrict__ W_bias,
    const float* __restrict__ W_f,  const float* __restrict__ W1,
    const float* __restrict__ W2,
    unsigned short* __restrict__ wf,
    int* __restrict__ wcnt, int* __restrict__ perm)
{
    const int vb = blockIdx.x, tid = threadIdx.x;
    __shared__ int wc8[8][MM];

    if (vb < NFRAGBLK) {
        // ---- weight convert (B-fragment-linear, hi/lo split); 512 elems ----
        unsigned short* dhi = wf + (size_t)vb * FB;
        unsigned short* dlo = dhi + 512;
        const int el = tid;
        const int ln = el >> 3, j = el & 7;
        const int krel = ((ln >> 4) << 3) + j;    // 0..31
        const int nrel = ln & 15;
        float v;
        if (vb < 512) {
            const int bb = vb & 255;
            const int kc = bb & 3, nt = (bb >> 2) & 7, m = bb >> 5;
            const float* src = (vb < 256 ? W_in : W_bias) + (size_t)m * EE * EE;
            v = src[(size_t)(kc*32 + krel) * EE + nt*16 + nrel];
        } else if (vb < 1024) {
            const int bb = vb - 512;
            const int kc = bb & 7, nt = (bb >> 3) & 7, m = bb >> 6;
            v = W_f[(size_t)m * 2*EE*EE + (size_t)(kc*32 + krel) * EE + nt*16 + nrel];
        } else if (vb < 1088) {
            const int bb = vb - 1024;
            const int kc = bb & 3, nt = bb >> 2;
            v = W1[(size_t)(kc*32 + krel) * HH + nt*16 + nrel];
        } else {
            const int kc = vb - 1088;
            v = W2[(size_t)(kc*32 + krel) * CC + nrel];
        }
        split1(v, dhi[el], dlo[el]);
    } else {
        // ---- segmented scatter: block = (t, seg of 512 samples) ----
        const int u = vb - NFRAGBLK;              // 0..23
        const int t = u >> 3, seg = u & 7;
        const int lane = tid & 63, wave = tid >> 6;
        const int s = seg*512 + tid;
        const int m = module_ids[s*NSTEPS + t];
        unsigned long long mybal = 0ull, lanebal = 0ull;
        #pragma unroll
        for (int k = 0; k < MM; k++) {
            const unsigned long long bk = __ballot(m == k);
            if (m == k)    mybal   = bk;          // static index: cndmask
            if (lane == k) lanebal = bk;
        }
        if (lane < MM) wc8[wave][lane] = __popcll(lanebal);
        __syncthreads();
        int base = 0;
        #pragma unroll
        for (int w = 0; w < 8; w++) if (w < wave) base += wc8[w][m];
        const unsigned long long below = (1ull << lane) - 1ull;
        const int rank = __popcll(mybal & below);
        perm[(((t*MM + m)*NSEG) + seg)*512 + base + rank] = s;
        if (tid < MM) {
            int sum = 0;
            #pragma unroll
            for (int w = 0; w < 8; w++) sum += wc8[w][tid];
            wcnt[((t*MM + tid)*NSEG) + seg] = sum;
        }
    }
}

// ---------------------------------------------------------------------------
// step: one recurrent step (8 waves, wave = n-tile). Embedding rows gathered
// fp32 directly, split in-register. For the LAST step the classifier head is
// fused in-block: x never round-trips through global.
// ---------------------------------------------------------------------------
__global__ __launch_bounds__(512, 2) void step_kernel(
    const int t,
    const int*   __restrict__ entity_ids,
    const float* __restrict__ embedding,
    const float* __restrict__ b_in, const float* __restrict__ b_bias,
    const float* __restrict__ b_f,
    const float* __restrict__ b1v, const float* __restrict__ b2,
    const unsigned short* __restrict__ wf,
    const int* __restrict__ wcnt, const int* __restrict__ perm,
    unsigned short* __restrict__ xsh, unsigned short* __restrict__ xsl,
    float* __restrict__ out)
{
    const int bx = blockIdx.x, tid = threadIdx.x;
    const int lane = tid & 63, wave = tid >> 6;          // wave = n-tile (0..7)
    const int row16 = lane & 15, quad = lane >> 4;

    // uniform bucket map for this step from per-segment counts
    int tot[MM];
    #pragma unroll
    for (int k = 0; k < MM; k++) {
        int s = 0;
        #pragma unroll
        for (int j = 0; j < NSEG; j++) s += wcnt[(t*MM + k)*NSEG + j];
        tot[k] = s;
    }
    int m = -1, pref = 0, cm = 0, acc = 0;
    #pragma unroll
    for (int k = 0; k < MM; k++) {
        const int nbk = (tot[k] + TS - 1) >> 4;
        if (m < 0 && bx < acc + nbk) { m = k; pref = acc; cm = tot[k]; }
        acc += nbk;
    }
    if (m < 0) return;                                   // bx >= NB
    const int chunk = bx - pref;

    __shared__ __align__(16) unsigned short hfh[8][512]; // frag-linear A, hi
    __shared__ __align__(16) unsigned short hfl[8][512]; // lo
    __shared__ int   sids[TS];
    __shared__ float red[8][TS][CC];

    if (tid < TS) {
        const int sl = chunk*TS + tid;
        int sv = -1;
        if (sl < cm) {
            int j = 0, r = sl;
            while (true) {
                const int c = wcnt[(t*MM + m)*NSEG + j];
                if (r < c) break;
                r -= c; j++;
            }
            sv = perm[((t*MM + m)*NSEG + j)*512 + r];
        }
        sids[tid] = sv;
    }
    __syncthreads();

    const int sA  = sids[row16];
    const int sAc = sA < 0 ? 0 : sA;

    // operand fragments: x (xh/xl) and bias-embedding (eh/el, direct gather)
    bf16x8 xh[4], xl[4], eh[4], el_[4];
    const int eidb = entity_ids[sAc*(NSTEPS+1) + t + 1];
    const float* srcb = embedding + (size_t)eidb*EE;

    if (t == 0) {
        const int eid0 = entity_ids[sAc*(NSTEPS+1)];
        const float* src0 = embedding + (size_t)eid0*EE;
        #pragma unroll
        for (int kc = 0; kc < 4; kc++) {
            const int off = kc*32 + quad*8;
            float vv[8], bb[8];
            *(float4*)(vv)     = *(const float4*)(src0 + off);
            *(float4*)(vv + 4) = *(const float4*)(src0 + off + 4);
            *(float4*)(bb)     = *(const float4*)(srcb + off);
            *(float4*)(bb + 4) = *(const float4*)(srcb + off + 4);
            split8(vv, xh[kc], xl[kc]);
            split8(bb, eh[kc], el_[kc]);
        }
    } else {
        const unsigned short* xhp = xsh + (size_t)sAc*EE;
        const unsigned short* xlp = xsl + (size_t)sAc*EE;
        #pragma unroll
        for (int kc = 0; kc < 4; kc++) {
            const int off = kc*32 + quad*8;
            float bb[8];
            *(float4*)(bb)     = *(const float4*)(srcb + off);
            *(float4*)(bb + 4) = *(const float4*)(srcb + off + 4);
            xh[kc] = *(const bf16x8*)(xhp + off);
            xl[kc] = *(const bf16x8*)(xlp + off);
            split8(bb, eh[kc], el_[kc]);
        }
    }

    // phase 1: h_in, h_bi for this wave's 16 output cols
    f32x4 aci = {0.f,0.f,0.f,0.f}, acb = {0.f,0.f,0.f,0.f};
    #pragma unroll
    for (int kc = 0; kc < 4; kc++) {
        const unsigned short* bI  = wf + (size_t)((m*8 + wave)*4 + kc)*FB;
        const unsigned short* bBp = wf + (size_t)(256 + (m*8 + wave)*4 + kc)*FB;
        const bf16x8 wih = *(const bf16x8*)(bI + lane*8);
        const bf16x8 wil = *(const bf16x8*)(bI + 512 + lane*8);
        const bf16x8 wbh = *(const bf16x8*)(bBp + lane*8);
        const bf16x8 wbl = *(const bf16x8*)(bBp + 512 + lane*8);
        aci = mfma3(xh[kc], xl[kc], wih, wil, aci);
        acb = mfma3(eh[kc], el_[kc], wbh, wbl, acb);
    }

    // epilogue 1: relu+bias, producer-side split, frag-linear LDS store
    {
        const int col = wave*16 + row16;
        const float bin = b_in [m*EE + col];
        const float bbi = b_bias[m*EE + col];
        #pragma unroll
        for (int r = 0; r < 4; r++) {
            const int row = quad*4 + r;
            {   // h_in -> k = col
                const float v = fmaxf(aci[r] + bin, 0.f);
                const int k = col, kc = k >> 5;
                const int idx = (row + 16*((k >> 3) & 3))*8 + (k & 7);
                split1(v, hfh[kc][idx], hfl[kc][idx]);
            }
            {   // h_bi -> k = 128 + col
                const float v = fmaxf(acb[r] + bbi, 0.f);
                const int k = EE + col, kc = k >> 5;
                const int idx = (row + 16*((k >> 3) & 3))*8 + (k & 7);
                split1(v, hfh[kc][idx], hfl[kc][idx]);
            }
        }
    }
    __syncthreads();

    // phase 2: x_new = tanh(h W_f + b_f), K = 256
    f32x4 acf = {0.f,0.f,0.f,0.f};
    #pragma unroll
    for (int kc = 0; kc < 8; kc++) {
        const bf16x8 ah = *(const bf16x8*)(&hfh[kc][lane*8]);
        const bf16x8 al = *(const bf16x8*)(&hfl[kc][lane*8]);
        const unsigned short* bF = wf + (size_t)(512 + (m*8 + wave)*8 + kc)*FB;
        const bf16x8 wfh = *(const bf16x8*)(bF + lane*8);
        const bf16x8 wfl = *(const bf16x8*)(bF + 512 + lane*8);
        acf = mfma3(ah, al, wfh, wfl, acf);
    }

    const int col = wave*16 + row16;
    const float bfv = b_f[m*EE + col];
    float xv[4];
    #pragma unroll
    for (int r = 0; r < 4; r++) xv[r] = tanhf(acf[r] + bfv);

    if (t < NSTEPS-1) {
        // write x_new for next step
        #pragma unroll
        for (int r = 0; r < 4; r++) {
            const int s = sids[quad*4 + r];
            if (s >= 0) {
                unsigned short h, l;
                split1(xv[r], h, l);
                xsh[(size_t)s*EE + col] = h;
                xsl[(size_t)s*EE + col] = l;
            }
        }
    } else {
        // ---- fused head: x stays on-chip ----
        __syncthreads();               // all waves done reading hf (phase 2)
        #pragma unroll
        for (int r = 0; r < 4; r++) {  // restage x split into hf kc 0..3
            const int row = quad*4 + r;
            const int k = col, kc = k >> 5;
            const int idx = (row + 16*((k >> 3) & 3))*8 + (k & 7);
            split1(xv[r], hfh[kc][idx], hfl[kc][idx]);
        }
        __syncthreads();

        // h = relu(x W1 + b1): 16 n-tiles, 2 per wave
        f32x4 a1[2] = {{0.f,0.f,0.f,0.f},{0.f,0.f,0.f,0.f}};
        #pragma unroll
        for (int i = 0; i < 2; i++) {
            const int nt = wave + 8*i;
            #pragma unroll
            for (int kc = 0; kc < 4; kc++) {
                const unsigned short* bW = wf + (size_t)(1024 + nt*4 + kc)*FB;
                const bf16x8 wh = *(const bf16x8*)(bW + lane*8);
                const bf16x8 wl = *(const bf16x8*)(bW + 512 + lane*8);
                const bf16x8 ah = *(const bf16x8*)(&hfh[kc][lane*8]);
                const bf16x8 al = *(const bf16x8*)(&hfl[kc][lane*8]);
                a1[i] = mfma3(ah, al, wh, wl, a1[i]);
            }
        }
        __syncthreads();               // done reading x-region before h overwrite
        #pragma unroll
        for (int i = 0; i < 2; i++) {
            const int c2 = (wave + 8*i)*16 + row16;      // 0..255
            const float b = b1v[c2];
            #pragma unroll
            for (int r = 0; r < 4; r++) {
                const int row = quad*4 + r;
                const float v = fmaxf(a1[i][r] + b, 0.f);
                const int kc = c2 >> 5;
                const int idx = (row + 16*((c2 >> 3) & 3))*8 + (c2 & 7);
                split1(v, hfh[kc][idx], hfl[kc][idx]);
            }
        }
        __syncthreads();

        // out = h W2 + b2: K-split, wave = kc
        f32x4 a2 = {0.f,0.f,0.f,0.f};
        {
            const int kc = wave;
            const bf16x8 ah = *(const bf16x8*)(&hfh[kc][lane*8]);
            const bf16x8 al = *(const bf16x8*)(&hfl[kc][lane*8]);
            const unsigned short* bW = wf + (size_t)(1088 + kc)*FB;
            const bf16x8 wh = *(const bf16x8*)(bW + lane*8);
            const bf16x8 wl = *(const bf16x8*)(bW + 512 + lane*8);
            a2 = mfma3(ah, al, wh, wl, a2);
        }
        #pragma unroll
        for (int r = 0; r < 4; r++) red[wave][quad*4 + r][row16] = a2[r];
        __syncthreads();

        if (tid < TS*CC) {
            const int sr = sids[tid >> 4];
            if (sr >= 0) {
                const int c = tid & 15;
                float v = b2[c];
                #pragma unroll
                for (int w = 0; w < 8; w++) v += red[w][tid >> 4][c];
                out[(size_t)sr*CC + c] = v;
            }
        }
    }
}

// ---------------------------------------------------------------------------
extern "C" void kernel_launch(void* const* d_in, const int* in_sizes, int n_in,
                              void* d_out, int out_size, void* d_ws, size_t ws_size,
                              hipStream_t stream) {
    const int*   entity_ids = (const int*)  d_in[0];
    const int*   module_ids = (const int*)  d_in[1];
    const float* embedding  = (const float*)d_in[2];
    const float* W_in   = (const float*)d_in[3];
    const float* b_in   = (const float*)d_in[4];
    const float* W_bias = (const float*)d_in[5];
    const float* b_bias = (const float*)d_in[6];
    const float* W_f    = (const float*)d_in[7];
    const float* b_f    = (const float*)d_in[8];
    const float* W1     = (const float*)d_in[9];
    const float* b1     = (const float*)d_in[10];
    const float* W2     = (const float*)d_in[11];
    const float* b2     = (const float*)d_in[12];
    float* out = (float*)d_out;

    char* ws = (char*)d_ws;
    int* wcnt = (int*)(ws + 0);                           // 768 B
    int* perm = (int*)(ws + 4096);                        // 3*8*8*512*4 = 384 KB
    unsigned short* wfb = (unsigned short*)(ws + (1u<<20));     // 2.25 MB
    unsigned short* xsh = (unsigned short*)(ws + (4u<<20));     // 1 MB each
    unsigned short* xsl = (unsigned short*)(ws + (5u<<20));

    prep_kernel<<<PREP_GRID, 512, 0, stream>>>(module_ids,
                                               W_in, W_bias, W_f, W1, W2,
                                               wfb, wcnt, perm);
    for (int t = 0; t < NSTEPS; t++) {
        step_kernel<<<NBMAX, 512, 0, stream>>>(t, entity_ids, embedding,
                                               b_in, b_bias, b_f, b1, b2,
                                               wfb, wcnt, perm, xsh, xsl, out);
    }
}

// Round 5
// 356.448 us; speedup vs baseline: 1.1401x; 1.0258x over previous
//
#include <hip/hip_runtime.h>

// Problem constants (from reference)
#define BB      4096
#define EE      128
#define MM      8
#define NSTEPS  3
#define HH      256
#define CC      16

#define TS      16                    // samples per tile (MFMA M-tile)
#define FB      1024                  // ushorts per weight frag-block (512 hi + 512 lo)

// frag-block ranges in wf:
//   W_in  : (m*8+nt)*4+kc            -> [0,256)
//   W_bias: 256 + (m*8+nt)*4+kc      -> [256,512)
//   W_f   : 512 + (m*8+nt)*8+kc      -> [512,1024)
//   W1    : 1024 + nt*4+kc (nt<16)   -> [1024,1088)
//   W2    : 1088 + kc      (kc<8)    -> [1088,1096)
#define NFRAGBLK 1096

#define NSEG    8                     // scatter segments per step (4096/512)
#define NBMAX   (BB/TS + MM)          // 264 worst-case bucket tiles per step
#define PREP_G  512                   // gather vblocks (16384 rows / 32)
#define PREP_GRID (NFRAGBLK + PREP_G + NSTEPS*NSEG)   // 1096+512+24 = 1632

typedef __attribute__((ext_vector_type(8))) short  bf16x8;
typedef __attribute__((ext_vector_type(4))) float  f32x4;

__device__ __forceinline__ unsigned short bf16_rn(float v) {
    unsigned u = __float_as_uint(v);
    return (unsigned short)((u + 0x7FFFu + ((u >> 16) & 1u)) >> 16);
}
__device__ __forceinline__ float bf16_f(unsigned short h) {
    return __uint_as_float(((unsigned)h) << 16);
}
__device__ __forceinline__ void split8(const float* v, bf16x8& hi, bf16x8& lo) {
    #pragma unroll
    for (int i = 0; i < 8; i++) {
        unsigned short h = bf16_rn(v[i]);
        hi[i] = (short)h;
        lo[i] = (short)bf16_rn(v[i] - bf16_f(h));
    }
}
__device__ __forceinline__ void split1(float v, unsigned short& h, unsigned short& l) {
    h = bf16_rn(v);
    l = bf16_rn(v - bf16_f(h));
}
#define MFMA(a,b,c) __builtin_amdgcn_mfma_f32_16x16x32_bf16((a),(b),(c),0,0,0)
__device__ __forceinline__ f32x4 mfma3(bf16x8 ah, bf16x8 al, bf16x8 bh, bf16x8 bl, f32x4 c) {
    c = MFMA(ah, bh, c);
    c = MFMA(ah, bl, c);
    c = MFMA(al, bh, c);
    return c;
}

// ---------------------------------------------------------------------------
// prep: weight convert | embedding gather-split (prestage: high-TLP here so
// the serial step chain never eats gather latency — R4 lesson) | deterministic
// segmented scatter (no atomics -> no memset node needed).
// ---------------------------------------------------------------------------
__global__ __launch_bounds__(512) void prep_kernel(
    const int*   __restrict__ entity_ids, const int* __restrict__ module_ids,
    const float* __restrict__ embedding,
    const float* __restrict__ W_in, const float* __restrict__ W_bias,
    const float* __restrict__ W_f,  const float* __restrict__ W1,
    const float* __restrict__ W2,
    unsigned short* __restrict__ wf,
    unsigned short* __restrict__ x0h, unsigned short* __restrict__ x0l,
    unsigned short* __restrict__ ebh, unsigned short* __restrict__ ebl,
    int* __restrict__ wcnt, int* __restrict__ perm)
{
    const int vb = blockIdx.x, tid = threadIdx.x;
    __shared__ int wc8[8][MM];

    if (vb < NFRAGBLK) {
        // ---- weight convert (B-fragment-linear, hi/lo split); 512 elems ----
        unsigned short* dhi = wf + (size_t)vb * FB;
        unsigned short* dlo = dhi + 512;
        const int el = tid;
        const int ln = el >> 3, j = el & 7;
        const int krel = ((ln >> 4) << 3) + j;    // 0..31
        const int nrel = ln & 15;
        float v;
        if (vb < 512) {
            const int bb = vb & 255;
            const int kc = bb & 3, nt = (bb >> 2) & 7, m = bb >> 5;
            const float* src = (vb < 256 ? W_in : W_bias) + (size_t)m * EE * EE;
            v = src[(size_t)(kc*32 + krel) * EE + nt*16 + nrel];
        } else if (vb < 1024) {
            const int bb = vb - 512;
            const int kc = bb & 7, nt = (bb >> 3) & 7, m = bb >> 6;
            v = W_f[(size_t)m * 2*EE*EE + (size_t)(kc*32 + krel) * EE + nt*16 + nrel];
        } else if (vb < 1088) {
            const int bb = vb - 1024;
            const int kc = bb & 3, nt = bb >> 2;
            v = W1[(size_t)(kc*32 + krel) * HH + nt*16 + nrel];
        } else {
            const int kc = vb - 1088;
            v = W2[(size_t)(kc*32 + krel) * CC + nrel];
        }
        split1(v, dhi[el], dlo[el]);
    } else if (vb < NFRAGBLK + PREP_G) {
        // ---- embedding gather + split: 32 rows per vblock ----
        const int u = vb - NFRAGBLK;              // 0..511
        const int rloc = tid >> 4, cpart = tid & 15;
        const int rglob = u*32 + rloc;            // 0..16383
        const int g = rglob >> 12;                // 0=x0, 1..3=bias step g-1
        const int s = rglob & (BB-1);
        const int eid = entity_ids[s*(NSTEPS+1) + g];
        const float* src = embedding + (size_t)eid*EE + cpart*8;
        float vv[8];
        *(float4*)(vv)     = *(const float4*)(src);
        *(float4*)(vv + 4) = *(const float4*)(src + 4);
        bf16x8 hi, lo;
        split8(vv, hi, lo);
        unsigned short* dh = (g == 0 ? x0h : ebh + (size_t)(g-1)*BB*EE) + (size_t)s*EE + cpart*8;
        unsigned short* dl = (g == 0 ? x0l : ebl + (size_t)(g-1)*BB*EE) + (size_t)s*EE + cpart*8;
        *(bf16x8*)dh = hi;
        *(bf16x8*)dl = lo;
    } else {
        // ---- segmented scatter: block = (t, seg of 512 samples) ----
        const int u = vb - NFRAGBLK - PREP_G;     // 0..23
        const int t = u >> 3, seg = u & 7;
        const int lane = tid & 63, wave = tid >> 6;
        const int s = seg*512 + tid;
        const int m = module_ids[s*NSTEPS + t];
        unsigned long long mybal = 0ull, lanebal = 0ull;
        #pragma unroll
        for (int k = 0; k < MM; k++) {
            const unsigned long long bk = __ballot(m == k);
            if (m == k)    mybal   = bk;          // static index: cndmask
            if (lane == k) lanebal = bk;
        }
        if (lane < MM) wc8[wave][lane] = __popcll(lanebal);
        __syncthreads();
        int base = 0;
        #pragma unroll
        for (int w = 0; w < 8; w++) if (w < wave) base += wc8[w][m];
        const unsigned long long below = (1ull << lane) - 1ull;
        const int rank = __popcll(mybal & below);
        perm[(((t*MM + m)*NSEG) + seg)*512 + base + rank] = s;
        if (tid < MM) {
            int sum = 0;
            #pragma unroll
            for (int w = 0; w < 8; w++) sum += wc8[w][tid];
            wcnt[((t*MM + tid)*NSEG) + seg] = sum;
        }
    }
}

// ---------------------------------------------------------------------------
// step: one recurrent step (8 waves, wave = n-tile). All operands pre-split
// bf16 (prestaged). For the LAST step the classifier head is fused in-block:
// x never round-trips through global.
// ---------------------------------------------------------------------------
__global__ __launch_bounds__(512, 2) void step_kernel(
    const int t,
    const unsigned short* __restrict__ x0h, const unsigned short* __restrict__ x0l,
    const unsigned short* __restrict__ ebh, const unsigned short* __restrict__ ebl,
    const float* __restrict__ b_in, const float* __restrict__ b_bias,
    const float* __restrict__ b_f,
    const float* __restrict__ b1v, const float* __restrict__ b2,
    const unsigned short* __restrict__ wf,
    const int* __restrict__ wcnt, const int* __restrict__ perm,
    unsigned short* __restrict__ xsh, unsigned short* __restrict__ xsl,
    float* __restrict__ out)
{
    const int bx = blockIdx.x, tid = threadIdx.x;
    const int lane = tid & 63, wave = tid >> 6;          // wave = n-tile (0..7)
    const int row16 = lane & 15, quad = lane >> 4;

    // uniform bucket map for this step from per-segment counts
    int tot[MM];
    #pragma unroll
    for (int k = 0; k < MM; k++) {
        int s = 0;
        #pragma unroll
        for (int j = 0; j < NSEG; j++) s += wcnt[(t*MM + k)*NSEG + j];
        tot[k] = s;
    }
    int m = -1, pref = 0, cm = 0, acc = 0;
    #pragma unroll
    for (int k = 0; k < MM; k++) {
        const int nbk = (tot[k] + TS - 1) >> 4;
        if (m < 0 && bx < acc + nbk) { m = k; pref = acc; cm = tot[k]; }
        acc += nbk;
    }
    if (m < 0) return;                                   // bx >= NB
    const int chunk = bx - pref;

    __shared__ __align__(16) unsigned short hfh[8][512]; // frag-linear A, hi
    __shared__ __align__(16) unsigned short hfl[8][512]; // lo
    __shared__ int   sids[TS];
    __shared__ float red[8][TS][CC];

    if (tid < TS) {
        const int sl = chunk*TS + tid;
        int sv = -1;
        if (sl < cm) {
            int j = 0, r = sl;
            while (true) {
                const int c = wcnt[(t*MM + m)*NSEG + j];
                if (r < c) break;
                r -= c; j++;
            }
            sv = perm[((t*MM + m)*NSEG + j)*512 + r];
        }
        sids[tid] = sv;
    }
    __syncthreads();

    const int sA  = sids[row16];
    const int sAc = sA < 0 ? 0 : sA;

    const unsigned short* xh_p = (t == 0 ? x0h : xsh) + (size_t)sAc*EE;
    const unsigned short* xl_p = (t == 0 ? x0l : xsl) + (size_t)sAc*EE;
    const unsigned short* eh_p = ebh + (size_t)t*BB*EE + (size_t)sAc*EE;
    const unsigned short* el_p = ebl + (size_t)t*BB*EE + (size_t)sAc*EE;

    bf16x8 xh[4], xl[4], eh[4], el_[4];
    #pragma unroll
    for (int kc = 0; kc < 4; kc++) {
        const int off = kc*32 + quad*8;
        xh[kc]  = *(const bf16x8*)(xh_p + off);
        xl[kc]  = *(const bf16x8*)(xl_p + off);
        eh[kc]  = *(const bf16x8*)(eh_p + off);
        el_[kc] = *(const bf16x8*)(el_p + off);
    }

    // phase 1: h_in, h_bi for this wave's 16 output cols
    f32x4 aci = {0.f,0.f,0.f,0.f}, acb = {0.f,0.f,0.f,0.f};
    #pragma unroll
    for (int kc = 0; kc < 4; kc++) {
        const unsigned short* bI  = wf + (size_t)((m*8 + wave)*4 + kc)*FB;
        const unsigned short* bBp = wf + (size_t)(256 + (m*8 + wave)*4 + kc)*FB;
        const bf16x8 wih = *(const bf16x8*)(bI + lane*8);
        const bf16x8 wil = *(const bf16x8*)(bI + 512 + lane*8);
        const bf16x8 wbh = *(const bf16x8*)(bBp + lane*8);
        const bf16x8 wbl = *(const bf16x8*)(bBp + 512 + lane*8);
        aci = mfma3(xh[kc], xl[kc], wih, wil, aci);
        acb = mfma3(eh[kc], el_[kc], wbh, wbl, acb);
    }

    // epilogue 1: relu+bias, producer-side split, frag-linear LDS store
    {
        const int col = wave*16 + row16;
        const float bin = b_in [m*EE + col];
        const float bbi = b_bias[m*EE + col];
        #pragma unroll
        for (int r = 0; r < 4; r++) {
            const int row = quad*4 + r;
            {   // h_in -> k = col
                const float v = fmaxf(aci[r] + bin, 0.f);
                const int k = col, kc = k >> 5;
                const int idx = (row + 16*((k >> 3) & 3))*8 + (k & 7);
                split1(v, hfh[kc][idx], hfl[kc][idx]);
            }
            {   // h_bi -> k = 128 + col
                const float v = fmaxf(acb[r] + bbi, 0.f);
                const int k = EE + col, kc = k >> 5;
                const int idx = (row + 16*((k >> 3) & 3))*8 + (k & 7);
                split1(v, hfh[kc][idx], hfl[kc][idx]);
            }
        }
    }
    __syncthreads();

    // phase 2: x_new = tanh(h W_f + b_f), K = 256
    f32x4 acf = {0.f,0.f,0.f,0.f};
    #pragma unroll
    for (int kc = 0; kc < 8; kc++) {
        const bf16x8 ah = *(const bf16x8*)(&hfh[kc][lane*8]);
        const bf16x8 al = *(const bf16x8*)(&hfl[kc][lane*8]);
        const unsigned short* bF = wf + (size_t)(512 + (m*8 + wave)*8 + kc)*FB;
        const bf16x8 wfh = *(const bf16x8*)(bF + lane*8);
        const bf16x8 wfl = *(const bf16x8*)(bF + 512 + lane*8);
        acf = mfma3(ah, al, wfh, wfl, acf);
    }

    const int col = wave*16 + row16;
    const float bfv = b_f[m*EE + col];
    float xv[4];
    #pragma unroll
    for (int r = 0; r < 4; r++) xv[r] = tanhf(acf[r] + bfv);

    if (t < NSTEPS-1) {
        // write x_new for next step
        #pragma unroll
        for (int r = 0; r < 4; r++) {
            const int s = sids[quad*4 + r];
            if (s >= 0) {
                unsigned short h, l;
                split1(xv[r], h, l);
                xsh[(size_t)s*EE + col] = h;
                xsl[(size_t)s*EE + col] = l;
            }
        }
    } else {
        // ---- fused head: x stays on-chip ----
        __syncthreads();               // all waves done reading hf (phase 2)
        #pragma unroll
        for (int r = 0; r < 4; r++) {  // restage x split into hf kc 0..3
            const int row = quad*4 + r;
            const int k = col, kc = k >> 5;
            const int idx = (row + 16*((k >> 3) & 3))*8 + (k & 7);
            split1(xv[r], hfh[kc][idx], hfl[kc][idx]);
        }
        __syncthreads();

        // h = relu(x W1 + b1): 16 n-tiles, 2 per wave
        f32x4 a1[2] = {{0.f,0.f,0.f,0.f},{0.f,0.f,0.f,0.f}};
        #pragma unroll
        for (int i = 0; i < 2; i++) {
            const int nt = wave + 8*i;
            #pragma unroll
            for (int kc = 0; kc < 4; kc++) {
                const unsigned short* bW = wf + (size_t)(1024 + nt*4 + kc)*FB;
                const bf16x8 wh = *(const bf16x8*)(bW + lane*8);
                const bf16x8 wl = *(const bf16x8*)(bW + 512 + lane*8);
                const bf16x8 ah = *(const bf16x8*)(&hfh[kc][lane*8]);
                const bf16x8 al = *(const bf16x8*)(&hfl[kc][lane*8]);
                a1[i] = mfma3(ah, al, wh, wl, a1[i]);
            }
        }
        __syncthreads();               // done reading x-region before h overwrite
        #pragma unroll
        for (int i = 0; i < 2; i++) {
            const int c2 = (wave + 8*i)*16 + row16;      // 0..255
            const float b = b1v[c2];
            #pragma unroll
            for (int r = 0; r < 4; r++) {
                const int row = quad*4 + r;
                const float v = fmaxf(a1[i][r] + b, 0.f);
                const int kc = c2 >> 5;
                const int idx = (row + 16*((c2 >> 3) & 3))*8 + (c2 & 7);
                split1(v, hfh[kc][idx], hfl[kc][idx]);
            }
        }
        __syncthreads();

        // out = h W2 + b2: K-split, wave = kc
        f32x4 a2 = {0.f,0.f,0.f,0.f};
        {
            const int kc = wave;
            const bf16x8 ah = *(const bf16x8*)(&hfh[kc][lane*8]);
            const bf16x8 al = *(const bf16x8*)(&hfl[kc][lane*8]);
            const unsigned short* bW = wf + (size_t)(1088 + kc)*FB;
            const bf16x8 wh = *(const bf16x8*)(bW + lane*8);
            const bf16x8 wl = *(const bf16x8*)(bW + 512 + lane*8);
            a2 = mfma3(ah, al, wh, wl, a2);
        }
        #pragma unroll
        for (int r = 0; r < 4; r++) red[wave][quad*4 + r][row16] = a2[r];
        __syncthreads();

        if (tid < TS*CC) {
            const int sr = sids[tid >> 4];
            if (sr >= 0) {
                const int c = tid & 15;
                float v = b2[c];
                #pragma unroll
                for (int w = 0; w < 8; w++) v += red[w][tid >> 4][c];
                out[(size_t)sr*CC + c] = v;
            }
        }
    }
}

// ---------------------------------------------------------------------------
extern "C" void kernel_launch(void* const* d_in, const int* in_sizes, int n_in,
                              void* d_out, int out_size, void* d_ws, size_t ws_size,
                              hipStream_t stream) {
    const int*   entity_ids = (const int*)  d_in[0];
    const int*   module_ids = (const int*)  d_in[1];
    const float* embedding  = (const float*)d_in[2];
    const float* W_in   = (const float*)d_in[3];
    const float* b_in   = (const float*)d_in[4];
    const float* W_bias = (const float*)d_in[5];
    const float* b_bias = (const float*)d_in[6];
    const float* W_f    = (const float*)d_in[7];
    const float* b_f    = (const float*)d_in[8];
    const float* W1     = (const float*)d_in[9];
    const float* b1     = (const float*)d_in[10];
    const float* W2     = (const float*)d_in[11];
    const float* b2     = (const float*)d_in[12];
    float* out = (float*)d_out;

    char* ws = (char*)d_ws;
    int* wcnt = (int*)(ws + 0);                           // 768 B
    int* perm = (int*)(ws + 4096);                        // 3*8*8*512*4 = 384 KB
    unsigned short* wfb = (unsigned short*)(ws + (1u<<20));     // 2.25 MB
    unsigned short* x0h = (unsigned short*)(ws + (4u<<20));     // 1 MB each
    unsigned short* x0l = (unsigned short*)(ws + (5u<<20));
    unsigned short* xsh = (unsigned short*)(ws + (6u<<20));
    unsigned short* xsl = (unsigned short*)(ws + (7u<<20));
    unsigned short* ebh = (unsigned short*)(ws + (8u<<20));     // 3 MB (t-major)
    unsigned short* ebl = (unsigned short*)(ws + (11u<<20));    // 3 MB

    prep_kernel<<<PREP_GRID, 512, 0, stream>>>(entity_ids, module_ids, embedding,
                                               W_in, W_bias, W_f, W1, W2,
                                               wfb, x0h, x0l, ebh, ebl, wcnt, perm);
    for (int t = 0; t < NSTEPS; t++) {
        step_kernel<<<NBMAX, 512, 0, stream>>>(t, x0h, x0l, ebh, ebl,
                                               b_in, b_bias, b_f, b1, b2,
                                               wfb, wcnt, perm, xsh, xsl, out);
    }
}